// Round 13
// baseline (308.236 us; speedup 1.0000x reference)
//
#include <hip/hip_runtime.h>

typedef short bfrag8 __attribute__((ext_vector_type(8)));
typedef float f32x4 __attribute__((ext_vector_type(4)));
typedef unsigned int uint4v __attribute__((ext_vector_type(4)));

#define SCAN_BLK 2048

// ---------- helpers ----------
__device__ __forceinline__ unsigned short f2bf(float f) {
    unsigned u = __float_as_uint(f);
    u += 0x7fffu + ((u >> 16) & 1u);   // round-to-nearest-even
    return (unsigned short)(u >> 16);
}
__device__ __forceinline__ float bf2f(unsigned short s) {
    return __uint_as_float((unsigned)s << 16);
}
__device__ __forceinline__ bfrag8 pack8(float4 a, float4 b) {
    bfrag8 r;
    r[0] = (short)f2bf(a.x); r[1] = (short)f2bf(a.y);
    r[2] = (short)f2bf(a.z); r[3] = (short)f2bf(a.w);
    r[4] = (short)f2bf(b.x); r[5] = (short)f2bf(b.y);
    r[6] = (short)f2bf(b.z); r[7] = (short)f2bf(b.w);
    return r;
}

// ---------- K1: fused prologue ----------
// [0,512):   zero cnt
// [512,768): pack W1 (65536 items)
// [768,896): pack W2 (32768 items)
// [896,...): gstart build + rs[N]=E+N
__global__ __launch_bounds__(256) void prologue(int* __restrict__ cnt,
                                                const float* __restrict__ W1,
                                                const float* __restrict__ W2,
                                                unsigned short* __restrict__ wf1,
                                                unsigned short* __restrict__ wf2,
                                                const int* __restrict__ batch,
                                                int* __restrict__ gstart,
                                                int* __restrict__ rs,
                                                int N, int G, int E) {
    const int b = blockIdx.x, t = threadIdx.x;
    if (b < 512) {
        int i = b * 256 + t;
        if (i < N) cnt[i] = 0;
    } else if (b < 768) {
        int i = (b - 512) * 256 + t;
        int e = i & 7, l = (i >> 3) & 63, c = (i >> 9) & 3, s = (i >> 11) & 3, h = i >> 13;
        int k = s * 32 + (l >> 4) * 8 + e;
        int col = h * 64 + c * 16 + (l & 15);
        wf1[i] = f2bf(W1[k * 512 + col]);
    } else if (b < 896) {
        int i = (b - 768) * 256 + t;
        int e = i & 7, l = (i >> 3) & 63, c = (i >> 9) & 3, s = i >> 11;
        int k = s * 32 + (l >> 4) * 8 + e;
        int col = c * 16 + (l & 15);
        wf2[i] = f2bf(W2[k * 64 + col]);
    } else {
        int i = (b - 896) * 256 + t;
        if (i == 0) rs[N] = E + N;
        if (i > N) return;
        if (i == N) {
            int p = batch[N - 1];
            for (int g = p + 1; g <= G; ++g) gstart[g] = N;
        } else {
            int bb = batch[i];
            int p = (i == 0) ? -1 : batch[i - 1];
            for (int g = p + 1; g <= bb; ++g) gstart[g] = i;
        }
    }
}

// ---------- K2: MFMA GEMM L1 (fp32 x, 2 heads per block, 4x head-pair blocks) + hist tail ----------
__global__ __launch_bounds__(256) void gemm_l1_hist(const float* __restrict__ x,
                                                    const unsigned short* __restrict__ Bfrag,
                                                    unsigned short* __restrict__ Cbf,
                                                    int M,
                                                    const float* __restrict__ avs,
                                                    const float* __restrict__ avd,
                                                    float* __restrict__ as_,
                                                    float* __restrict__ ad_,
                                                    int gemmBlocks, int rowBlocks,
                                                    const int* __restrict__ ei,
                                                    int* __restrict__ cnt, int E) {
    const int b = blockIdx.x;
    if (b >= gemmBlocks) {
        int t = (b - gemmBlocks) * 256 + threadIdx.x;
        if (t < E + M) {
            int dst = (t < E) ? ei[E + t] : t - E;
            atomicAdd(cnt + dst, 1);
        }
        return;
    }
    const int rb = b % rowBlocks;        // row block
    const int hp = b / rowBlocks;        // head pair 0..3
    const int lane = threadIdx.x & 63;
    const int wave = threadIdx.x >> 6;
    const int l15 = lane & 15, l16 = lane >> 4;
    const long rowBase = (long)rb * 128 + wave * 32;

    long r0 = rowBase + l15;        if (r0 > M - 1) r0 = M - 1;
    long r1 = rowBase + 16 + l15;   if (r1 > M - 1) r1 = M - 1;

    // A fragments: read x fp32, convert in-register (x is L3-resident; read 4x total)
    bfrag8 a0f[4], a1f[4];
#pragma unroll
    for (int s = 0; s < 4; ++s) {
        const float* p0 = x + r0 * 128 + s * 32 + l16 * 8;
        const float* p1 = x + r1 * 128 + s * 32 + l16 * 8;
        float4 u0 = *(const float4*)p0, u1 = *(const float4*)(p0 + 4);
        float4 v0 = *(const float4*)p1, v1 = *(const float4*)(p1 + 4);
        a0f[s] = pack8(u0, u1);
        a1f[s] = pack8(v0, v1);
    }

#pragma unroll 1
    for (int hh = 0; hh < 2; ++hh) {
        const int h = hp * 2 + hh;
        bfrag8 bf[4][4];
        const bfrag8* bp = (const bfrag8*)(Bfrag + (size_t)h * 8192);
#pragma unroll
        for (int s = 0; s < 4; ++s)
#pragma unroll
            for (int c = 0; c < 4; ++c)
                bf[s][c] = bp[(s * 4 + c) * 64 + lane];

        f32x4 acc[2][4];
#pragma unroll
        for (int r = 0; r < 2; ++r)
#pragma unroll
            for (int c = 0; c < 4; ++c)
#pragma unroll
                for (int e = 0; e < 4; ++e) acc[r][c][e] = 0.f;

#pragma unroll
        for (int s = 0; s < 4; ++s) {
#pragma unroll
            for (int c = 0; c < 4; ++c) {
                acc[0][c] = __builtin_amdgcn_mfma_f32_16x16x32_bf16(a0f[s], bf[s][c], acc[0][c], 0, 0, 0);
                acc[1][c] = __builtin_amdgcn_mfma_f32_16x16x32_bf16(a1f[s], bf[s][c], acc[1][c], 0, 0, 0);
            }
        }

        float avsv[4], avdv[4];
#pragma unroll
        for (int c = 0; c < 4; ++c) {
            avsv[c] = avs[h * 64 + c * 16 + l15];
            avdv[c] = avd[h * 64 + c * 16 + l15];
        }

#pragma unroll
        for (int r = 0; r < 2; ++r) {
#pragma unroll
            for (int reg = 0; reg < 4; ++reg) {
                long row = rowBase + r * 16 + l16 * 4 + reg;
                bool ok = row < M;
                float ps = 0.f, pd = 0.f;
#pragma unroll
                for (int c = 0; c < 4; ++c) {
                    float v = acc[r][c][reg];
                    if (ok) Cbf[row * 512 + h * 64 + c * 16 + l15] = f2bf(v);
                    ps += v * avsv[c];
                    pd += v * avdv[c];
                }
#pragma unroll
                for (int off = 1; off < 16; off <<= 1) {
                    ps += __shfl_xor(ps, off);
                    pd += __shfl_xor(pd, off);
                }
                if (l15 == 0 && ok) {
                    as_[row * 8 + h] = ps;
                    ad_[row * 8 + h] = pd;
                }
            }
        }
    }
}

// ---------- K3: per-chunk scan ----------
__global__ __launch_bounds__(256) void scan1(const int* __restrict__ cnt,
                                             int* __restrict__ rs,
                                             int* __restrict__ bsum, int N) {
    __shared__ int lds[256];
    int base = blockIdx.x * SCAN_BLK;
    int vals[8];
    int tsum = 0;
    int idx0 = base + threadIdx.x * 8;
#pragma unroll
    for (int j = 0; j < 8; ++j) {
        int i = idx0 + j;
        int v = (i < N) ? cnt[i] : 0;
        vals[j] = tsum;
        tsum += v;
    }
    lds[threadIdx.x] = tsum;
    __syncthreads();
    for (int off = 1; off < 256; off <<= 1) {
        int v = lds[threadIdx.x];
        int u = (threadIdx.x >= (unsigned)off) ? lds[threadIdx.x - off] : 0;
        __syncthreads();
        lds[threadIdx.x] = v + u;
        __syncthreads();
    }
    int texcl = (threadIdx.x == 0) ? 0 : lds[threadIdx.x - 1];
#pragma unroll
    for (int j = 0; j < 8; ++j) {
        int i = idx0 + j;
        if (i < N) rs[i] = texcl + vals[j];
    }
    if (threadIdx.x == 255) bsum[blockIdx.x] = lds[255];
}

// ---------- K4: scan fixup ----------
__global__ __launch_bounds__(256) void scan_fix(int* __restrict__ rs,
                                                const int* __restrict__ bsum, int N) {
    __shared__ int sprefix;
    int b = blockIdx.x;
    int i = b * 256 + threadIdx.x;
    int chunk = (b * 256) / SCAN_BLK;
    if (threadIdx.x == 0) {
        int p = 0;
        for (int k = 0; k < chunk; ++k) p += bsum[k];
        sprefix = p;
    }
    __syncthreads();
    if (i < N) rs[i] += sprefix;
}

// ---------- K5: scatter via count-down ----------
__global__ __launch_bounds__(256) void scatter_cd(const int* __restrict__ ei,
                                                  const int* __restrict__ rs,
                                                  int* __restrict__ cnt,
                                                  int* __restrict__ csrc, int E, int N) {
    int t = (int)(blockIdx.x * 256u + threadIdx.x);
    if (t >= E + N) return;
    int src, dst;
    if (t < E) { src = ei[t]; dst = ei[E + t]; } else { src = dst = t - E; }
    int pos = rs[dst] + atomicSub(cnt + dst, 1) - 1;
    csrc[pos] = src;
}

// ---------- K6: gather over all 8 heads (unroll-4 + scalar tail; measured-best) ----------
__global__ __launch_bounds__(256) void gather8(const int* __restrict__ csrc,
                                               const int* __restrict__ rs,
                                               const float* __restrict__ as_,  // [N][8]
                                               const float* __restrict__ ad_,  // [N][8]
                                               const unsigned short* __restrict__ h, // [N][512]
                                               const float* __restrict__ bias,      // [512]
                                               unsigned short* __restrict__ outp,   // [N][512]
                                               int N) {
    int node = (int)((blockIdx.x * 256u + threadIdx.x) >> 6);
    int lane = threadIdx.x & 63;
    if (node >= N) return;
    int myh = lane >> 3;
    int s0 = rs[node], s1 = rs[node + 1];
    float adn = ad_[(size_t)node * 8 + myh];
    float den = 0.f;
    float2 acc[4] = {};
    const unsigned* hu = (const unsigned*)h;
    int k = s0;
    for (; k + 4 <= s1; k += 4) {
        int i0 = csrc[k], i1 = csrc[k + 1], i2 = csrc[k + 2], i3 = csrc[k + 3];
        float a0 = as_[(size_t)i0 * 8 + myh] + adn;
        float a1 = as_[(size_t)i1 * 8 + myh] + adn;
        float a2 = as_[(size_t)i2 * 8 + myh] + adn;
        float a3 = as_[(size_t)i3 * 8 + myh] + adn;
        a0 = a0 > 0.f ? a0 : 0.2f * a0;  a1 = a1 > 0.f ? a1 : 0.2f * a1;
        a2 = a2 > 0.f ? a2 : 0.2f * a2;  a3 = a3 > 0.f ? a3 : 0.2f * a3;
        float w0 = __expf(fminf(a0, 60.f)), w1 = __expf(fminf(a1, 60.f));
        float w2 = __expf(fminf(a2, 60.f)), w3 = __expf(fminf(a3, 60.f));
        uint4v v0 = *(const uint4v*)(hu + (size_t)i0 * 256 + lane * 4);
        uint4v v1 = *(const uint4v*)(hu + (size_t)i1 * 256 + lane * 4);
        uint4v v2 = *(const uint4v*)(hu + (size_t)i2 * 256 + lane * 4);
        uint4v v3 = *(const uint4v*)(hu + (size_t)i3 * 256 + lane * 4);
        den += (w0 + w1) + (w2 + w3);
#pragma unroll
        for (int j = 0; j < 4; ++j) {
            acc[j].x += w0 * __uint_as_float(v0[j] << 16);
            acc[j].y += w0 * __uint_as_float(v0[j] & 0xffff0000u);
            acc[j].x += w1 * __uint_as_float(v1[j] << 16);
            acc[j].y += w1 * __uint_as_float(v1[j] & 0xffff0000u);
            acc[j].x += w2 * __uint_as_float(v2[j] << 16);
            acc[j].y += w2 * __uint_as_float(v2[j] & 0xffff0000u);
            acc[j].x += w3 * __uint_as_float(v3[j] << 16);
            acc[j].y += w3 * __uint_as_float(v3[j] & 0xffff0000u);
        }
    }
    for (; k < s1; ++k) {
        int i0 = csrc[k];
        float a = as_[(size_t)i0 * 8 + myh] + adn;
        a = a > 0.f ? a : 0.2f * a;
        float w = __expf(fminf(a, 60.f));
        uint4v v0 = *(const uint4v*)(hu + (size_t)i0 * 256 + lane * 4);
        den += w;
#pragma unroll
        for (int j = 0; j < 4; ++j) {
            acc[j].x += w * __uint_as_float(v0[j] << 16);
            acc[j].y += w * __uint_as_float(v0[j] & 0xffff0000u);
        }
    }
    float rden = 1.f / (den + 1e-16f);
    uint4v o;
#pragma unroll
    for (int j = 0; j < 4; ++j) {
        float vlo = acc[j].x * rden + bias[lane * 8 + 2 * j];
        float vhi = acc[j].y * rden + bias[lane * 8 + 2 * j + 1];
        vlo = vlo > 0.f ? vlo : 0.f;
        vhi = vhi > 0.f ? vhi : 0.f;
        o[j] = (unsigned)f2bf(vlo) | ((unsigned)f2bf(vhi) << 16);
    }
    *(uint4v*)(outp + (size_t)node * 512 + lane * 8) = o;
}

// ---------- K7: MFMA GEMM L2 (K=512) + attn2 dots ----------
__global__ __launch_bounds__(256) void gemm_l2_k512(const unsigned short* __restrict__ A,
                                                    const unsigned short* __restrict__ Bfrag,
                                                    unsigned short* __restrict__ Cbf,
                                                    int M,
                                                    const float* __restrict__ avs,
                                                    const float* __restrict__ avd,
                                                    float* __restrict__ as_,
                                                    float* __restrict__ ad_) {
    const int lane = threadIdx.x & 63;
    const int wave = threadIdx.x >> 6;
    const int l15 = lane & 15, l16 = lane >> 4;
    const long rowBase = (long)blockIdx.x * 128 + wave * 32;
    const bfrag8* bp = (const bfrag8*)Bfrag;

    f32x4 acc[2][4];
#pragma unroll
    for (int r = 0; r < 2; ++r)
#pragma unroll
        for (int c = 0; c < 4; ++c)
#pragma unroll
            for (int e = 0; e < 4; ++e) acc[r][c][e] = 0.f;

    long r0 = rowBase + l15;        if (r0 > M - 1) r0 = M - 1;
    long r1 = rowBase + 16 + l15;   if (r1 > M - 1) r1 = M - 1;
    const unsigned short* a0p = A + r0 * 512 + l16 * 8;
    const unsigned short* a1p = A + r1 * 512 + l16 * 8;

    for (int s = 0; s < 16; ++s) {
        bfrag8 a0 = *(const bfrag8*)(a0p + s * 32);
        bfrag8 a1 = *(const bfrag8*)(a1p + s * 32);
        bfrag8 bf0 = bp[(s * 4 + 0) * 64 + lane];
        bfrag8 bf1 = bp[(s * 4 + 1) * 64 + lane];
        bfrag8 bf2 = bp[(s * 4 + 2) * 64 + lane];
        bfrag8 bf3 = bp[(s * 4 + 3) * 64 + lane];
        acc[0][0] = __builtin_amdgcn_mfma_f32_16x16x32_bf16(a0, bf0, acc[0][0], 0, 0, 0);
        acc[1][0] = __builtin_amdgcn_mfma_f32_16x16x32_bf16(a1, bf0, acc[1][0], 0, 0, 0);
        acc[0][1] = __builtin_amdgcn_mfma_f32_16x16x32_bf16(a0, bf1, acc[0][1], 0, 0, 0);
        acc[1][1] = __builtin_amdgcn_mfma_f32_16x16x32_bf16(a1, bf1, acc[1][1], 0, 0, 0);
        acc[0][2] = __builtin_amdgcn_mfma_f32_16x16x32_bf16(a0, bf2, acc[0][2], 0, 0, 0);
        acc[1][2] = __builtin_amdgcn_mfma_f32_16x16x32_bf16(a1, bf2, acc[1][2], 0, 0, 0);
        acc[0][3] = __builtin_amdgcn_mfma_f32_16x16x32_bf16(a0, bf3, acc[0][3], 0, 0, 0);
        acc[1][3] = __builtin_amdgcn_mfma_f32_16x16x32_bf16(a1, bf3, acc[1][3], 0, 0, 0);
    }

    float avsv[4], avdv[4];
#pragma unroll
    for (int c = 0; c < 4; ++c) {
        avsv[c] = avs[c * 16 + l15];
        avdv[c] = avd[c * 16 + l15];
    }

#pragma unroll
    for (int r = 0; r < 2; ++r) {
#pragma unroll
        for (int reg = 0; reg < 4; ++reg) {
            long row = rowBase + r * 16 + l16 * 4 + reg;
            bool ok = row < M;
            float ps = 0.f, pd = 0.f;
#pragma unroll
            for (int c = 0; c < 4; ++c) {
                float v = acc[r][c][reg];
                if (ok) Cbf[row * 64 + c * 16 + l15] = f2bf(v);
                ps += v * avsv[c];
                pd += v * avdv[c];
            }
#pragma unroll
            for (int off = 1; off < 16; off <<= 1) {
                ps += __shfl_xor(ps, off);
                pd += __shfl_xor(pd, off);
            }
            if (l15 == 0 && ok) { as_[row] = ps; ad_[row] = pd; }
        }
    }
}

// ---------- K8: single-head gather -> f32 out ----------
__global__ __launch_bounds__(256) void gather1(const int* __restrict__ csrc,
                                               const int* __restrict__ rs,
                                               const float* __restrict__ as_,
                                               const float* __restrict__ ad_,
                                               const unsigned short* __restrict__ h,
                                               const float* __restrict__ bias,
                                               float* __restrict__ outp, int N) {
    int node = (int)((blockIdx.x * 256u + threadIdx.x) >> 6);
    int lane = threadIdx.x & 63;
    if (node >= N) return;
    int s0 = rs[node], s1 = rs[node + 1];
    float adn = ad_[node];
    float den = 0.f, acc = 0.f;
    int k = s0;
    for (; k + 4 <= s1; k += 4) {
        int i0 = csrc[k], i1 = csrc[k + 1], i2 = csrc[k + 2], i3 = csrc[k + 3];
        float a0 = as_[i0] + adn, a1 = as_[i1] + adn, a2 = as_[i2] + adn, a3 = as_[i3] + adn;
        a0 = a0 > 0.f ? a0 : 0.2f * a0;  a1 = a1 > 0.f ? a1 : 0.2f * a1;
        a2 = a2 > 0.f ? a2 : 0.2f * a2;  a3 = a3 > 0.f ? a3 : 0.2f * a3;
        float w0 = __expf(fminf(a0, 60.f)), w1 = __expf(fminf(a1, 60.f));
        float w2 = __expf(fminf(a2, 60.f)), w3 = __expf(fminf(a3, 60.f));
        float h0 = bf2f(h[(size_t)i0 * 64 + lane]);
        float h1 = bf2f(h[(size_t)i1 * 64 + lane]);
        float h2 = bf2f(h[(size_t)i2 * 64 + lane]);
        float h3 = bf2f(h[(size_t)i3 * 64 + lane]);
        den += (w0 + w1) + (w2 + w3);
        acc += w0 * h0;  acc += w1 * h1;  acc += w2 * h2;  acc += w3 * h3;
    }
    for (; k < s1; ++k) {
        int i0 = csrc[k];
        float a = as_[i0] + adn;
        a = a > 0.f ? a : 0.2f * a;
        float w = __expf(fminf(a, 60.f));
        den += w;
        acc += w * bf2f(h[(size_t)i0 * 64 + lane]);
    }
    float v = acc / (den + 1e-16f) + bias[lane];
    outp[(size_t)node * 64 + lane] = v > 0.f ? v : 0.f;
}

// ---------- K9: fused mean-pool + readout ----------
__global__ __launch_bounds__(256) void pool_readout(const float* __restrict__ h2,
                                                    const int* __restrict__ gstart,
                                                    const float* __restrict__ Wf,
                                                    const float* __restrict__ bf,
                                                    float* __restrict__ out, int G) {
    int g = (int)((blockIdx.x * 256u + threadIdx.x) >> 6);
    int lane = threadIdx.x & 63;
    if (g >= G) return;
    int s0 = gstart[g], s1 = gstart[g + 1];
    float acc = 0.f;
    int i = s0;
    for (; i + 2 <= s1; i += 2) {
        acc += h2[(size_t)i * 64 + lane];
        acc += h2[(size_t)(i + 1) * 64 + lane];
    }
    if (i < s1) acc += h2[(size_t)i * 64 + lane];
    float c = (float)(s1 - s0);
    c = c < 1.f ? 1.f : c;
    float v = acc / c * Wf[lane];
#pragma unroll
    for (int off = 32; off; off >>= 1) v += __shfl_xor(v, off);
    if (lane == 0) out[g] = v + bf[0];
}

extern "C" void kernel_launch(void* const* d_in, const int* in_sizes, int n_in,
                              void* d_out, int out_size, void* d_ws, size_t ws_size,
                              hipStream_t stream) {
    const float* x        = (const float*)d_in[0];
    const int*   ei       = (const int*)d_in[1];
    const int*   batch    = (const int*)d_in[2];
    const float* W1       = (const float*)d_in[3];
    const float* att_src1 = (const float*)d_in[4];
    const float* att_dst1 = (const float*)d_in[5];
    const float* b1       = (const float*)d_in[6];
    const float* W2       = (const float*)d_in[7];
    const float* att_src2 = (const float*)d_in[8];
    const float* att_dst2 = (const float*)d_in[9];
    const float* b2       = (const float*)d_in[10];
    const float* Wf       = (const float*)d_in[11];
    const float* bf       = (const float*)d_in[12];
    float* out = (float*)d_out;

    const int N = in_sizes[2];        // 100000
    const int E = in_sizes[1] / 2;    // 400000
    const int G = out_size;           // 4096

    const int nb = (N + SCAN_BLK - 1) / SCAN_BLK;
    const int nodeWaveGrid = (int)(((size_t)N * 64 + 255) / 256);
    const int edgeGrid = (E + N + 255) / 256;
    const int gemmGrid = (N + 127) / 128;

    // ---- workspace layout ----
    char* base = (char*)d_ws;
    size_t off = 0;
    auto alloc = [&](size_t bytes) { char* p = base + off; off += (bytes + 255) & ~255llu; return p; };
    unsigned short* wf1   = (unsigned short*)alloc(131072);
    unsigned short* wf2   = (unsigned short*)alloc(65536);
    float* as1            = (float*)alloc((size_t)N * 8 * 4);
    float* ad1            = (float*)alloc((size_t)N * 8 * 4);
    float* as2            = (float*)alloc((size_t)N * 4);
    float* ad2            = (float*)alloc((size_t)N * 4);
    int*   cnt_i          = (int*)alloc((size_t)N * 4);
    int*   rs             = (int*)alloc((size_t)(N + 1) * 4);
    int*   csrc           = (int*)alloc((size_t)(E + N) * 4);
    int*   bsum           = (int*)alloc(1024);
    int*   gstart         = (int*)alloc((size_t)(G + 1) * 4);
    float* ob2            = (float*)alloc((size_t)N * 64 * 4);
    unsigned short* h2bf  = (unsigned short*)alloc((size_t)N * 64 * 2);
    unsigned short* h1_bf = (unsigned short*)alloc((size_t)N * 512 * 2);
    unsigned short* ob1_bf= (unsigned short*)alloc((size_t)N * 512 * 2);
    (void)ws_size;

    // ---- K1: prologue (zero + weight pack + gstart) ----
    {
        int gsBlocks = (N + 256) / 256 + 1;
        prologue<<<896 + gsBlocks, 256, 0, stream>>>(cnt_i, W1, W2, wf1, wf2,
                                                     batch, gstart, rs, N, G, E);
    }

    // ---- K2: layer-1 GEMM (4 head-pair block groups) + histogram tail ----
    {
        int gemmBlocks = gemmGrid * 4;
        gemm_l1_hist<<<gemmBlocks + edgeGrid, 256, 0, stream>>>(
            x, wf1, h1_bf, N, att_src1, att_dst1, as1, ad1,
            gemmBlocks, gemmGrid, ei, cnt_i, E);
    }

    // ---- K3-K5: scan + scatter ----
    scan1<<<nb, 256, 0, stream>>>(cnt_i, rs, bsum, N);
    scan_fix<<<(N + 255) / 256, 256, 0, stream>>>(rs, bsum, N);
    scatter_cd<<<edgeGrid, 256, 0, stream>>>(ei, rs, cnt_i, csrc, E, N);

    // ---- K6: layer-1 aggregation (all heads, single pass) ----
    gather8<<<nodeWaveGrid, 256, 0, stream>>>(csrc, rs, as1, ad1, h1_bf, b1, ob1_bf, N);

    // ---- K7: layer-2 GEMM (K=512) + attn2 dots ----
    gemm_l2_k512<<<gemmGrid, 256, 0, stream>>>(ob1_bf, wf2, h2bf, N,
                                               att_src2, att_dst2, as2, ad2);

    // ---- K8: layer-2 aggregation ----
    gather1<<<nodeWaveGrid, 256, 0, stream>>>(csrc, rs, as2, ad2, h2bf, b2, ob2, N);

    // ---- K9: pool + readout ----
    pool_readout<<<(G * 64 + 255) / 256, 256, 0, stream>>>(ob2, gstart, Wf, bf, out, G);
}

// Round 14
// 278.429 us; speedup vs baseline: 1.1071x; 1.1071x over previous
//
#include <hip/hip_runtime.h>

typedef short bfrag8 __attribute__((ext_vector_type(8)));
typedef float f32x4 __attribute__((ext_vector_type(4)));
typedef unsigned int uint4v __attribute__((ext_vector_type(4)));

#define SCAN_BLK 2048

// ---------- helpers ----------
__device__ __forceinline__ unsigned short f2bf(float f) {
    unsigned u = __float_as_uint(f);
    u += 0x7fffu + ((u >> 16) & 1u);   // round-to-nearest-even
    return (unsigned short)(u >> 16);
}
__device__ __forceinline__ float bf2f(unsigned short s) {
    return __uint_as_float((unsigned)s << 16);
}
__device__ __forceinline__ bfrag8 pack8(float4 a, float4 b) {
    bfrag8 r;
    r[0] = (short)f2bf(a.x); r[1] = (short)f2bf(a.y);
    r[2] = (short)f2bf(a.z); r[3] = (short)f2bf(a.w);
    r[4] = (short)f2bf(b.x); r[5] = (short)f2bf(b.y);
    r[6] = (short)f2bf(b.z); r[7] = (short)f2bf(b.w);
    return r;
}

// ---------- K1: fused prologue ----------
// [0,512):   zero cnt
// [512,768): pack W1 (65536 items)
// [768,896): pack W2 (32768 items)
// [896,...): gstart build + rs[N]=E+N
__global__ __launch_bounds__(256) void prologue(int* __restrict__ cnt,
                                                const float* __restrict__ W1,
                                                const float* __restrict__ W2,
                                                unsigned short* __restrict__ wf1,
                                                unsigned short* __restrict__ wf2,
                                                const int* __restrict__ batch,
                                                int* __restrict__ gstart,
                                                int* __restrict__ rs,
                                                int N, int G, int E) {
    const int b = blockIdx.x, t = threadIdx.x;
    if (b < 512) {
        int i = b * 256 + t;
        if (i < N) cnt[i] = 0;
    } else if (b < 768) {
        int i = (b - 512) * 256 + t;
        int e = i & 7, l = (i >> 3) & 63, c = (i >> 9) & 3, s = (i >> 11) & 3, h = i >> 13;
        int k = s * 32 + (l >> 4) * 8 + e;
        int col = h * 64 + c * 16 + (l & 15);
        wf1[i] = f2bf(W1[k * 512 + col]);
    } else if (b < 896) {
        int i = (b - 768) * 256 + t;
        int e = i & 7, l = (i >> 3) & 63, c = (i >> 9) & 3, s = i >> 11;
        int k = s * 32 + (l >> 4) * 8 + e;
        int col = c * 16 + (l & 15);
        wf2[i] = f2bf(W2[k * 64 + col]);
    } else {
        int i = (b - 896) * 256 + t;
        if (i == 0) rs[N] = E + N;
        if (i > N) return;
        if (i == N) {
            int p = batch[N - 1];
            for (int g = p + 1; g <= G; ++g) gstart[g] = N;
        } else {
            int bb = batch[i];
            int p = (i == 0) ? -1 : batch[i - 1];
            for (int g = p + 1; g <= bb; ++g) gstart[g] = i;
        }
    }
}

// ---------- K2: MFMA GEMM L1, 64-row blocks (1 row-tile/wave), 8-head loop, hist tail ----------
__global__ __launch_bounds__(256) void gemm_l1_hist(const float* __restrict__ x,
                                                    const unsigned short* __restrict__ Bfrag,
                                                    unsigned short* __restrict__ Cbf,
                                                    int M,
                                                    const float* __restrict__ avs,
                                                    const float* __restrict__ avd,
                                                    float* __restrict__ as_,
                                                    float* __restrict__ ad_,
                                                    int gemmBlocks,
                                                    const int* __restrict__ ei,
                                                    int* __restrict__ cnt, int E) {
    const int b = blockIdx.x;
    if (b >= gemmBlocks) {
        int t = (b - gemmBlocks) * 256 + threadIdx.x;
        if (t < E + M) {
            int dst = (t < E) ? ei[E + t] : t - E;
            atomicAdd(cnt + dst, 1);
        }
        return;
    }
    const int lane = threadIdx.x & 63;
    const int wave = threadIdx.x >> 6;
    const int l15 = lane & 15, l16 = lane >> 4;
    const long rowBase = (long)b * 64 + wave * 16;   // 16 rows per wave

    long r0 = rowBase + l15;        if (r0 > M - 1) r0 = M - 1;

    // A fragments: read x fp32 once, convert in-register
    bfrag8 a0f[4];
#pragma unroll
    for (int s = 0; s < 4; ++s) {
        const float* p0 = x + r0 * 128 + s * 32 + l16 * 8;
        float4 u0 = *(const float4*)p0, u1 = *(const float4*)(p0 + 4);
        a0f[s] = pack8(u0, u1);
    }

#pragma unroll 1
    for (int h = 0; h < 8; ++h) {
        const bfrag8* bp = (const bfrag8*)(Bfrag + (size_t)h * 8192);

        f32x4 acc[4];
#pragma unroll
        for (int c = 0; c < 4; ++c)
#pragma unroll
            for (int e = 0; e < 4; ++e) acc[c][e] = 0.f;

#pragma unroll
        for (int s = 0; s < 4; ++s) {
            bfrag8 b0 = bp[(s * 4 + 0) * 64 + lane];
            bfrag8 b1 = bp[(s * 4 + 1) * 64 + lane];
            bfrag8 b2 = bp[(s * 4 + 2) * 64 + lane];
            bfrag8 b3 = bp[(s * 4 + 3) * 64 + lane];
            acc[0] = __builtin_amdgcn_mfma_f32_16x16x32_bf16(a0f[s], b0, acc[0], 0, 0, 0);
            acc[1] = __builtin_amdgcn_mfma_f32_16x16x32_bf16(a0f[s], b1, acc[1], 0, 0, 0);
            acc[2] = __builtin_amdgcn_mfma_f32_16x16x32_bf16(a0f[s], b2, acc[2], 0, 0, 0);
            acc[3] = __builtin_amdgcn_mfma_f32_16x16x32_bf16(a0f[s], b3, acc[3], 0, 0, 0);
        }

        float avsv[4], avdv[4];
#pragma unroll
        for (int c = 0; c < 4; ++c) {
            avsv[c] = avs[h * 64 + c * 16 + l15];
            avdv[c] = avd[h * 64 + c * 16 + l15];
        }

#pragma unroll
        for (int reg = 0; reg < 4; ++reg) {
            long row = rowBase + l16 * 4 + reg;
            bool ok = row < M;
            float ps = 0.f, pd = 0.f;
#pragma unroll
            for (int c = 0; c < 4; ++c) {
                float v = acc[c][reg];
                if (ok) Cbf[row * 512 + h * 64 + c * 16 + l15] = f2bf(v);
                ps += v * avsv[c];
                pd += v * avdv[c];
            }
#pragma unroll
            for (int off = 1; off < 16; off <<= 1) {
                ps += __shfl_xor(ps, off);
                pd += __shfl_xor(pd, off);
            }
            if (l15 == 0 && ok) {
                as_[row * 8 + h] = ps;
                ad_[row * 8 + h] = pd;
            }
        }
    }
}

// ---------- K3: per-chunk scan ----------
__global__ __launch_bounds__(256) void scan1(const int* __restrict__ cnt,
                                             int* __restrict__ rs,
                                             int* __restrict__ bsum, int N) {
    __shared__ int lds[256];
    int base = blockIdx.x * SCAN_BLK;
    int vals[8];
    int tsum = 0;
    int idx0 = base + threadIdx.x * 8;
#pragma unroll
    for (int j = 0; j < 8; ++j) {
        int i = idx0 + j;
        int v = (i < N) ? cnt[i] : 0;
        vals[j] = tsum;
        tsum += v;
    }
    lds[threadIdx.x] = tsum;
    __syncthreads();
    for (int off = 1; off < 256; off <<= 1) {
        int v = lds[threadIdx.x];
        int u = (threadIdx.x >= (unsigned)off) ? lds[threadIdx.x - off] : 0;
        __syncthreads();
        lds[threadIdx.x] = v + u;
        __syncthreads();
    }
    int texcl = (threadIdx.x == 0) ? 0 : lds[threadIdx.x - 1];
#pragma unroll
    for (int j = 0; j < 8; ++j) {
        int i = idx0 + j;
        if (i < N) rs[i] = texcl + vals[j];
    }
    if (threadIdx.x == 255) bsum[blockIdx.x] = lds[255];
}

// ---------- K4: scan fixup ----------
__global__ __launch_bounds__(256) void scan_fix(int* __restrict__ rs,
                                                const int* __restrict__ bsum, int N) {
    __shared__ int sprefix;
    int b = blockIdx.x;
    int i = b * 256 + threadIdx.x;
    int chunk = (b * 256) / SCAN_BLK;
    if (threadIdx.x == 0) {
        int p = 0;
        for (int k = 0; k < chunk; ++k) p += bsum[k];
        sprefix = p;
    }
    __syncthreads();
    if (i < N) rs[i] += sprefix;
}

// ---------- K5: scatter via count-down ----------
__global__ __launch_bounds__(256) void scatter_cd(const int* __restrict__ ei,
                                                  const int* __restrict__ rs,
                                                  int* __restrict__ cnt,
                                                  int* __restrict__ csrc, int E, int N) {
    int t = (int)(blockIdx.x * 256u + threadIdx.x);
    if (t >= E + N) return;
    int src, dst;
    if (t < E) { src = ei[t]; dst = ei[E + t]; } else { src = dst = t - E; }
    int pos = rs[dst] + atomicSub(cnt + dst, 1) - 1;
    csrc[pos] = src;
}

// ---------- K6: gather over all 8 heads (unroll-4 + scalar tail; measured-best) ----------
__global__ __launch_bounds__(256) void gather8(const int* __restrict__ csrc,
                                               const int* __restrict__ rs,
                                               const float* __restrict__ as_,  // [N][8]
                                               const float* __restrict__ ad_,  // [N][8]
                                               const unsigned short* __restrict__ h, // [N][512]
                                               const float* __restrict__ bias,      // [512]
                                               unsigned short* __restrict__ outp,   // [N][512]
                                               int N) {
    int node = (int)((blockIdx.x * 256u + threadIdx.x) >> 6);
    int lane = threadIdx.x & 63;
    if (node >= N) return;
    int myh = lane >> 3;
    int s0 = rs[node], s1 = rs[node + 1];
    float adn = ad_[(size_t)node * 8 + myh];
    float den = 0.f;
    float2 acc[4] = {};
    const unsigned* hu = (const unsigned*)h;
    int k = s0;
    for (; k + 4 <= s1; k += 4) {
        int i0 = csrc[k], i1 = csrc[k + 1], i2 = csrc[k + 2], i3 = csrc[k + 3];
        float a0 = as_[(size_t)i0 * 8 + myh] + adn;
        float a1 = as_[(size_t)i1 * 8 + myh] + adn;
        float a2 = as_[(size_t)i2 * 8 + myh] + adn;
        float a3 = as_[(size_t)i3 * 8 + myh] + adn;
        a0 = a0 > 0.f ? a0 : 0.2f * a0;  a1 = a1 > 0.f ? a1 : 0.2f * a1;
        a2 = a2 > 0.f ? a2 : 0.2f * a2;  a3 = a3 > 0.f ? a3 : 0.2f * a3;
        float w0 = __expf(fminf(a0, 60.f)), w1 = __expf(fminf(a1, 60.f));
        float w2 = __expf(fminf(a2, 60.f)), w3 = __expf(fminf(a3, 60.f));
        uint4v v0 = *(const uint4v*)(hu + (size_t)i0 * 256 + lane * 4);
        uint4v v1 = *(const uint4v*)(hu + (size_t)i1 * 256 + lane * 4);
        uint4v v2 = *(const uint4v*)(hu + (size_t)i2 * 256 + lane * 4);
        uint4v v3 = *(const uint4v*)(hu + (size_t)i3 * 256 + lane * 4);
        den += (w0 + w1) + (w2 + w3);
#pragma unroll
        for (int j = 0; j < 4; ++j) {
            acc[j].x += w0 * __uint_as_float(v0[j] << 16);
            acc[j].y += w0 * __uint_as_float(v0[j] & 0xffff0000u);
            acc[j].x += w1 * __uint_as_float(v1[j] << 16);
            acc[j].y += w1 * __uint_as_float(v1[j] & 0xffff0000u);
            acc[j].x += w2 * __uint_as_float(v2[j] << 16);
            acc[j].y += w2 * __uint_as_float(v2[j] & 0xffff0000u);
            acc[j].x += w3 * __uint_as_float(v3[j] << 16);
            acc[j].y += w3 * __uint_as_float(v3[j] & 0xffff0000u);
        }
    }
    for (; k < s1; ++k) {
        int i0 = csrc[k];
        float a = as_[(size_t)i0 * 8 + myh] + adn;
        a = a > 0.f ? a : 0.2f * a;
        float w = __expf(fminf(a, 60.f));
        uint4v v0 = *(const uint4v*)(hu + (size_t)i0 * 256 + lane * 4);
        den += w;
#pragma unroll
        for (int j = 0; j < 4; ++j) {
            acc[j].x += w * __uint_as_float(v0[j] << 16);
            acc[j].y += w * __uint_as_float(v0[j] & 0xffff0000u);
        }
    }
    float rden = 1.f / (den + 1e-16f);
    uint4v o;
#pragma unroll
    for (int j = 0; j < 4; ++j) {
        float vlo = acc[j].x * rden + bias[lane * 8 + 2 * j];
        float vhi = acc[j].y * rden + bias[lane * 8 + 2 * j + 1];
        vlo = vlo > 0.f ? vlo : 0.f;
        vhi = vhi > 0.f ? vhi : 0.f;
        o[j] = (unsigned)f2bf(vlo) | ((unsigned)f2bf(vhi) << 16);
    }
    *(uint4v*)(outp + (size_t)node * 512 + lane * 8) = o;
}

// ---------- K7: MFMA GEMM L2 (K=512) + attn2 dots ----------
__global__ __launch_bounds__(256) void gemm_l2_k512(const unsigned short* __restrict__ A,
                                                    const unsigned short* __restrict__ Bfrag,
                                                    unsigned short* __restrict__ Cbf,
                                                    int M,
                                                    const float* __restrict__ avs,
                                                    const float* __restrict__ avd,
                                                    float* __restrict__ as_,
                                                    float* __restrict__ ad_) {
    const int lane = threadIdx.x & 63;
    const int wave = threadIdx.x >> 6;
    const int l15 = lane & 15, l16 = lane >> 4;
    const long rowBase = (long)blockIdx.x * 128 + wave * 32;
    const bfrag8* bp = (const bfrag8*)Bfrag;

    f32x4 acc[2][4];
#pragma unroll
    for (int r = 0; r < 2; ++r)
#pragma unroll
        for (int c = 0; c < 4; ++c)
#pragma unroll
            for (int e = 0; e < 4; ++e) acc[r][c][e] = 0.f;

    long r0 = rowBase + l15;        if (r0 > M - 1) r0 = M - 1;
    long r1 = rowBase + 16 + l15;   if (r1 > M - 1) r1 = M - 1;
    const unsigned short* a0p = A + r0 * 512 + l16 * 8;
    const unsigned short* a1p = A + r1 * 512 + l16 * 8;

    for (int s = 0; s < 16; ++s) {
        bfrag8 a0 = *(const bfrag8*)(a0p + s * 32);
        bfrag8 a1 = *(const bfrag8*)(a1p + s * 32);
        bfrag8 bf0 = bp[(s * 4 + 0) * 64 + lane];
        bfrag8 bf1 = bp[(s * 4 + 1) * 64 + lane];
        bfrag8 bf2 = bp[(s * 4 + 2) * 64 + lane];
        bfrag8 bf3 = bp[(s * 4 + 3) * 64 + lane];
        acc[0][0] = __builtin_amdgcn_mfma_f32_16x16x32_bf16(a0, bf0, acc[0][0], 0, 0, 0);
        acc[1][0] = __builtin_amdgcn_mfma_f32_16x16x32_bf16(a1, bf0, acc[1][0], 0, 0, 0);
        acc[0][1] = __builtin_amdgcn_mfma_f32_16x16x32_bf16(a0, bf1, acc[0][1], 0, 0, 0);
        acc[1][1] = __builtin_amdgcn_mfma_f32_16x16x32_bf16(a1, bf1, acc[1][1], 0, 0, 0);
        acc[0][2] = __builtin_amdgcn_mfma_f32_16x16x32_bf16(a0, bf2, acc[0][2], 0, 0, 0);
        acc[1][2] = __builtin_amdgcn_mfma_f32_16x16x32_bf16(a1, bf2, acc[1][2], 0, 0, 0);
        acc[0][3] = __builtin_amdgcn_mfma_f32_16x16x32_bf16(a0, bf3, acc[0][3], 0, 0, 0);
        acc[1][3] = __builtin_amdgcn_mfma_f32_16x16x32_bf16(a1, bf3, acc[1][3], 0, 0, 0);
    }

    float avsv[4], avdv[4];
#pragma unroll
    for (int c = 0; c < 4; ++c) {
        avsv[c] = avs[c * 16 + l15];
        avdv[c] = avd[c * 16 + l15];
    }

#pragma unroll
    for (int r = 0; r < 2; ++r) {
#pragma unroll
        for (int reg = 0; reg < 4; ++reg) {
            long row = rowBase + r * 16 + l16 * 4 + reg;
            bool ok = row < M;
            float ps = 0.f, pd = 0.f;
#pragma unroll
            for (int c = 0; c < 4; ++c) {
                float v = acc[r][c][reg];
                if (ok) Cbf[row * 64 + c * 16 + l15] = f2bf(v);
                ps += v * avsv[c];
                pd += v * avdv[c];
            }
#pragma unroll
            for (int off = 1; off < 16; off <<= 1) {
                ps += __shfl_xor(ps, off);
                pd += __shfl_xor(pd, off);
            }
            if (l15 == 0 && ok) { as_[row] = ps; ad_[row] = pd; }
        }
    }
}

// ---------- K8: single-head gather -> f32 out ----------
__global__ __launch_bounds__(256) void gather1(const int* __restrict__ csrc,
                                               const int* __restrict__ rs,
                                               const float* __restrict__ as_,
                                               const float* __restrict__ ad_,
                                               const unsigned short* __restrict__ h,
                                               const float* __restrict__ bias,
                                               float* __restrict__ outp, int N) {
    int node = (int)((blockIdx.x * 256u + threadIdx.x) >> 6);
    int lane = threadIdx.x & 63;
    if (node >= N) return;
    int s0 = rs[node], s1 = rs[node + 1];
    float adn = ad_[node];
    float den = 0.f, acc = 0.f;
    int k = s0;
    for (; k + 4 <= s1; k += 4) {
        int i0 = csrc[k], i1 = csrc[k + 1], i2 = csrc[k + 2], i3 = csrc[k + 3];
        float a0 = as_[i0] + adn, a1 = as_[i1] + adn, a2 = as_[i2] + adn, a3 = as_[i3] + adn;
        a0 = a0 > 0.f ? a0 : 0.2f * a0;  a1 = a1 > 0.f ? a1 : 0.2f * a1;
        a2 = a2 > 0.f ? a2 : 0.2f * a2;  a3 = a3 > 0.f ? a3 : 0.2f * a3;
        float w0 = __expf(fminf(a0, 60.f)), w1 = __expf(fminf(a1, 60.f));
        float w2 = __expf(fminf(a2, 60.f)), w3 = __expf(fminf(a3, 60.f));
        float h0 = bf2f(h[(size_t)i0 * 64 + lane]);
        float h1 = bf2f(h[(size_t)i1 * 64 + lane]);
        float h2 = bf2f(h[(size_t)i2 * 64 + lane]);
        float h3 = bf2f(h[(size_t)i3 * 64 + lane]);
        den += (w0 + w1) + (w2 + w3);
        acc += w0 * h0;  acc += w1 * h1;  acc += w2 * h2;  acc += w3 * h3;
    }
    for (; k < s1; ++k) {
        int i0 = csrc[k];
        float a = as_[i0] + adn;
        a = a > 0.f ? a : 0.2f * a;
        float w = __expf(fminf(a, 60.f));
        den += w;
        acc += w * bf2f(h[(size_t)i0 * 64 + lane]);
    }
    float v = acc / (den + 1e-16f) + bias[lane];
    outp[(size_t)node * 64 + lane] = v > 0.f ? v : 0.f;
}

// ---------- K9: fused mean-pool + readout ----------
__global__ __launch_bounds__(256) void pool_readout(const float* __restrict__ h2,
                                                    const int* __restrict__ gstart,
                                                    const float* __restrict__ Wf,
                                                    const float* __restrict__ bf,
                                                    float* __restrict__ out, int G) {
    int g = (int)((blockIdx.x * 256u + threadIdx.x) >> 6);
    int lane = threadIdx.x & 63;
    if (g >= G) return;
    int s0 = gstart[g], s1 = gstart[g + 1];
    float acc = 0.f;
    int i = s0;
    for (; i + 2 <= s1; i += 2) {
        acc += h2[(size_t)i * 64 + lane];
        acc += h2[(size_t)(i + 1) * 64 + lane];
    }
    if (i < s1) acc += h2[(size_t)i * 64 + lane];
    float c = (float)(s1 - s0);
    c = c < 1.f ? 1.f : c;
    float v = acc / c * Wf[lane];
#pragma unroll
    for (int off = 32; off; off >>= 1) v += __shfl_xor(v, off);
    if (lane == 0) out[g] = v + bf[0];
}

extern "C" void kernel_launch(void* const* d_in, const int* in_sizes, int n_in,
                              void* d_out, int out_size, void* d_ws, size_t ws_size,
                              hipStream_t stream) {
    const float* x        = (const float*)d_in[0];
    const int*   ei       = (const int*)d_in[1];
    const int*   batch    = (const int*)d_in[2];
    const float* W1       = (const float*)d_in[3];
    const float* att_src1 = (const float*)d_in[4];
    const float* att_dst1 = (const float*)d_in[5];
    const float* b1       = (const float*)d_in[6];
    const float* W2       = (const float*)d_in[7];
    const float* att_src2 = (const float*)d_in[8];
    const float* att_dst2 = (const float*)d_in[9];
    const float* b2       = (const float*)d_in[10];
    const float* Wf       = (const float*)d_in[11];
    const float* bf       = (const float*)d_in[12];
    float* out = (float*)d_out;

    const int N = in_sizes[2];        // 100000
    const int E = in_sizes[1] / 2;    // 400000
    const int G = out_size;           // 4096

    const int nb = (N + SCAN_BLK - 1) / SCAN_BLK;
    const int nodeWaveGrid = (int)(((size_t)N * 64 + 255) / 256);
    const int edgeGrid = (E + N + 255) / 256;
    const int gemmGrid128 = (N + 127) / 128;
    const int gemmGrid64 = (N + 63) / 64;

    // ---- workspace layout ----
    char* base = (char*)d_ws;
    size_t off = 0;
    auto alloc = [&](size_t bytes) { char* p = base + off; off += (bytes + 255) & ~255llu; return p; };
    unsigned short* wf1   = (unsigned short*)alloc(131072);
    unsigned short* wf2   = (unsigned short*)alloc(65536);
    float* as1            = (float*)alloc((size_t)N * 8 * 4);
    float* ad1            = (float*)alloc((size_t)N * 8 * 4);
    float* as2            = (float*)alloc((size_t)N * 4);
    float* ad2            = (float*)alloc((size_t)N * 4);
    int*   cnt_i          = (int*)alloc((size_t)N * 4);
    int*   rs             = (int*)alloc((size_t)(N + 1) * 4);
    int*   csrc           = (int*)alloc((size_t)(E + N) * 4);
    int*   bsum           = (int*)alloc(1024);
    int*   gstart         = (int*)alloc((size_t)(G + 1) * 4);
    float* ob2            = (float*)alloc((size_t)N * 64 * 4);
    unsigned short* h2bf  = (unsigned short*)alloc((size_t)N * 64 * 2);
    unsigned short* h1_bf = (unsigned short*)alloc((size_t)N * 512 * 2);
    unsigned short* ob1_bf= (unsigned short*)alloc((size_t)N * 512 * 2);
    (void)ws_size;

    // ---- K1: prologue (zero + weight pack + gstart) ----
    {
        int gsBlocks = (N + 256) / 256 + 1;
        prologue<<<896 + gsBlocks, 256, 0, stream>>>(cnt_i, W1, W2, wf1, wf2,
                                                     batch, gstart, rs, N, G, E);
    }

    // ---- K2: layer-1 GEMM (64-row blocks, 8-head loop) + histogram tail ----
    gemm_l1_hist<<<gemmGrid64 + edgeGrid, 256, 0, stream>>>(
        x, wf1, h1_bf, N, att_src1, att_dst1, as1, ad1,
        gemmGrid64, ei, cnt_i, E);

    // ---- K3-K5: scan + scatter ----
    scan1<<<nb, 256, 0, stream>>>(cnt_i, rs, bsum, N);
    scan_fix<<<(N + 255) / 256, 256, 0, stream>>>(rs, bsum, N);
    scatter_cd<<<edgeGrid, 256, 0, stream>>>(ei, rs, cnt_i, csrc, E, N);

    // ---- K6: layer-1 aggregation (all heads, single pass) ----
    gather8<<<nodeWaveGrid, 256, 0, stream>>>(csrc, rs, as1, ad1, h1_bf, b1, ob1_bf, N);

    // ---- K7: layer-2 GEMM (K=512) + attn2 dots ----
    gemm_l2_k512<<<gemmGrid128, 256, 0, stream>>>(ob1_bf, wf2, h2bf, N,
                                                  att_src2, att_dst2, as2, ad2);

    // ---- K8: layer-2 aggregation ----
    gather1<<<nodeWaveGrid, 256, 0, stream>>>(csrc, rs, as2, ad2, h2bf, b2, ob2, N);

    // ---- K9: pool + readout ----
    pool_readout<<<(G * 64 + 255) / 256, 256, 0, stream>>>(ob2, gstart, Wf, bf, out, G);
}

// Round 15
// 274.715 us; speedup vs baseline: 1.1220x; 1.0135x over previous
//
#include <hip/hip_runtime.h>

typedef short bfrag8 __attribute__((ext_vector_type(8)));
typedef float f32x4 __attribute__((ext_vector_type(4)));
typedef unsigned int uint4v __attribute__((ext_vector_type(4)));

#define SCAN_BLK 2048

// ---------- helpers ----------
__device__ __forceinline__ unsigned short f2bf(float f) {
    unsigned u = __float_as_uint(f);
    u += 0x7fffu + ((u >> 16) & 1u);   // round-to-nearest-even
    return (unsigned short)(u >> 16);
}
__device__ __forceinline__ float bf2f(unsigned short s) {
    return __uint_as_float((unsigned)s << 16);
}
__device__ __forceinline__ bfrag8 pack8(float4 a, float4 b) {
    bfrag8 r;
    r[0] = (short)f2bf(a.x); r[1] = (short)f2bf(a.y);
    r[2] = (short)f2bf(a.z); r[3] = (short)f2bf(a.w);
    r[4] = (short)f2bf(b.x); r[5] = (short)f2bf(b.y);
    r[6] = (short)f2bf(b.z); r[7] = (short)f2bf(b.w);
    return r;
}

// ---------- K1: fused prologue ----------
__global__ __launch_bounds__(256) void prologue(int* __restrict__ cnt,
                                                const float* __restrict__ W1,
                                                const float* __restrict__ W2,
                                                unsigned short* __restrict__ wf1,
                                                unsigned short* __restrict__ wf2,
                                                const int* __restrict__ batch,
                                                int* __restrict__ gstart,
                                                int* __restrict__ rs,
                                                int N, int G, int E) {
    const int b = blockIdx.x, t = threadIdx.x;
    if (b < 512) {
        int i = b * 256 + t;
        if (i < N) cnt[i] = 0;
    } else if (b < 768) {
        int i = (b - 512) * 256 + t;
        int e = i & 7, l = (i >> 3) & 63, c = (i >> 9) & 3, s = (i >> 11) & 3, h = i >> 13;
        int k = s * 32 + (l >> 4) * 8 + e;
        int col = h * 64 + c * 16 + (l & 15);
        wf1[i] = f2bf(W1[k * 512 + col]);
    } else if (b < 896) {
        int i = (b - 768) * 256 + t;
        int e = i & 7, l = (i >> 3) & 63, c = (i >> 9) & 3, s = i >> 11;
        int k = s * 32 + (l >> 4) * 8 + e;
        int col = c * 16 + (l & 15);
        wf2[i] = f2bf(W2[k * 64 + col]);
    } else {
        int i = (b - 896) * 256 + t;
        if (i == 0) rs[N] = E + N;
        if (i > N) return;
        if (i == N) {
            int p = batch[N - 1];
            for (int g = p + 1; g <= G; ++g) gstart[g] = N;
        } else {
            int bb = batch[i];
            int p = (i == 0) ? -1 : batch[i - 1];
            for (int g = p + 1; g <= bb; ++g) gstart[g] = i;
        }
    }
}

// ---------- K2: MFMA GEMM L1, 64-row blocks, LDS-staged coalesced stores, hist tail ----------
__global__ __launch_bounds__(256) void gemm_l1_hist(const float* __restrict__ x,
                                                    const unsigned short* __restrict__ Bfrag,
                                                    unsigned short* __restrict__ Cbf,
                                                    int M,
                                                    const float* __restrict__ avs,
                                                    const float* __restrict__ avd,
                                                    float* __restrict__ as_,
                                                    float* __restrict__ ad_,
                                                    int gemmBlocks,
                                                    const int* __restrict__ ei,
                                                    int* __restrict__ cnt, int E) {
    const int b = blockIdx.x;
    if (b >= gemmBlocks) {
        int t = (b - gemmBlocks) * 256 + threadIdx.x;
        if (t < E + M) {
            int dst = (t < E) ? ei[E + t] : t - E;
            atomicAdd(cnt + dst, 1);
        }
        return;
    }
    __shared__ unsigned short lt[64][72];   // 9216 B; stride 144B (16B-aligned)
    const int tid = threadIdx.x;
    const int lane = tid & 63;
    const int wave = tid >> 6;
    const int l15 = lane & 15, l16 = lane >> 4;
    const long rowBase = (long)b * 64 + wave * 16;   // 16 rows per wave

    long r0 = rowBase + l15;        if (r0 > M - 1) r0 = M - 1;

    // A fragments: read x fp32 once, convert in-register
    bfrag8 a0f[4];
#pragma unroll
    for (int s = 0; s < 4; ++s) {
        const float* p0 = x + r0 * 128 + s * 32 + l16 * 8;
        float4 u0 = *(const float4*)p0, u1 = *(const float4*)(p0 + 4);
        a0f[s] = pack8(u0, u1);
    }

#pragma unroll 1
    for (int h = 0; h < 8; ++h) {
        const bfrag8* bp = (const bfrag8*)(Bfrag + (size_t)h * 8192);

        f32x4 acc[4];
#pragma unroll
        for (int c = 0; c < 4; ++c)
#pragma unroll
            for (int e = 0; e < 4; ++e) acc[c][e] = 0.f;

#pragma unroll
        for (int s = 0; s < 4; ++s) {
            bfrag8 b0 = bp[(s * 4 + 0) * 64 + lane];
            bfrag8 b1 = bp[(s * 4 + 1) * 64 + lane];
            bfrag8 b2 = bp[(s * 4 + 2) * 64 + lane];
            bfrag8 b3 = bp[(s * 4 + 3) * 64 + lane];
            acc[0] = __builtin_amdgcn_mfma_f32_16x16x32_bf16(a0f[s], b0, acc[0], 0, 0, 0);
            acc[1] = __builtin_amdgcn_mfma_f32_16x16x32_bf16(a0f[s], b1, acc[1], 0, 0, 0);
            acc[2] = __builtin_amdgcn_mfma_f32_16x16x32_bf16(a0f[s], b2, acc[2], 0, 0, 0);
            acc[3] = __builtin_amdgcn_mfma_f32_16x16x32_bf16(a0f[s], b3, acc[3], 0, 0, 0);
        }

        // stage C-tile into LDS (row-local = wave*16 + l16*4 + reg, col = c*16 + l15)
#pragma unroll
        for (int reg = 0; reg < 4; ++reg)
#pragma unroll
            for (int c = 0; c < 4; ++c)
                lt[wave * 16 + l16 * 4 + reg][c * 16 + l15] = f2bf(acc[c][reg]);

        // as/ad dots (register-only, hides barrier)
        float avsv[4], avdv[4];
#pragma unroll
        for (int c = 0; c < 4; ++c) {
            avsv[c] = avs[h * 64 + c * 16 + l15];
            avdv[c] = avd[h * 64 + c * 16 + l15];
        }
#pragma unroll
        for (int reg = 0; reg < 4; ++reg) {
            long row = rowBase + l16 * 4 + reg;
            bool ok = row < M;
            float ps = 0.f, pd = 0.f;
#pragma unroll
            for (int c = 0; c < 4; ++c) {
                ps += acc[c][reg] * avsv[c];
                pd += acc[c][reg] * avdv[c];
            }
#pragma unroll
            for (int off = 1; off < 16; off <<= 1) {
                ps += __shfl_xor(ps, off);
                pd += __shfl_xor(pd, off);
            }
            if (l15 == 0 && ok) {
                as_[row * 8 + h] = ps;
                ad_[row * 8 + h] = pd;
            }
        }
        __syncthreads();

        // coalesced readback + store: 8 threads per row, 16B each -> 128B/row segment
#pragma unroll
        for (int it = 0; it < 2; ++it) {
            int idx = it * 256 + tid;          // 0..511
            int row_l = idx >> 3;
            int cg = idx & 7;
            long row = (long)b * 64 + row_l;
            if (row < M) {
                uint4v v = *(const uint4v*)(&lt[row_l][cg * 8]);
                *(uint4v*)(Cbf + row * 512 + h * 64 + cg * 8) = v;
            }
        }
        __syncthreads();
    }
}

// ---------- K3: per-chunk scan ----------
__global__ __launch_bounds__(256) void scan1(const int* __restrict__ cnt,
                                             int* __restrict__ rs,
                                             int* __restrict__ bsum, int N) {
    __shared__ int lds[256];
    int base = blockIdx.x * SCAN_BLK;
    int vals[8];
    int tsum = 0;
    int idx0 = base + threadIdx.x * 8;
#pragma unroll
    for (int j = 0; j < 8; ++j) {
        int i = idx0 + j;
        int v = (i < N) ? cnt[i] : 0;
        vals[j] = tsum;
        tsum += v;
    }
    lds[threadIdx.x] = tsum;
    __syncthreads();
    for (int off = 1; off < 256; off <<= 1) {
        int v = lds[threadIdx.x];
        int u = (threadIdx.x >= (unsigned)off) ? lds[threadIdx.x - off] : 0;
        __syncthreads();
        lds[threadIdx.x] = v + u;
        __syncthreads();
    }
    int texcl = (threadIdx.x == 0) ? 0 : lds[threadIdx.x - 1];
#pragma unroll
    for (int j = 0; j < 8; ++j) {
        int i = idx0 + j;
        if (i < N) rs[i] = texcl + vals[j];
    }
    if (threadIdx.x == 255) bsum[blockIdx.x] = lds[255];
}

// ---------- K4: scan fixup ----------
__global__ __launch_bounds__(256) void scan_fix(int* __restrict__ rs,
                                                const int* __restrict__ bsum, int N) {
    __shared__ int sprefix;
    int b = blockIdx.x;
    int i = b * 256 + threadIdx.x;
    int chunk = (b * 256) / SCAN_BLK;
    if (threadIdx.x == 0) {
        int p = 0;
        for (int k = 0; k < chunk; ++k) p += bsum[k];
        sprefix = p;
    }
    __syncthreads();
    if (i < N) rs[i] += sprefix;
}

// ---------- K5: scatter via count-down ----------
__global__ __launch_bounds__(256) void scatter_cd(const int* __restrict__ ei,
                                                  const int* __restrict__ rs,
                                                  int* __restrict__ cnt,
                                                  int* __restrict__ csrc, int E, int N) {
    int t = (int)(blockIdx.x * 256u + threadIdx.x);
    if (t >= E + N) return;
    int src, dst;
    if (t < E) { src = ei[t]; dst = ei[E + t]; } else { src = dst = t - E; }
    int pos = rs[dst] + atomicSub(cnt + dst, 1) - 1;
    csrc[pos] = src;
}

// ---------- K6: gather over all 8 heads (unroll-4 + scalar tail; measured-best) ----------
__global__ __launch_bounds__(256) void gather8(const int* __restrict__ csrc,
                                               const int* __restrict__ rs,
                                               const float* __restrict__ as_,  // [N][8]
                                               const float* __restrict__ ad_,  // [N][8]
                                               const unsigned short* __restrict__ h, // [N][512]
                                               const float* __restrict__ bias,      // [512]
                                               unsigned short* __restrict__ outp,   // [N][512]
                                               int N) {
    int node = (int)((blockIdx.x * 256u + threadIdx.x) >> 6);
    int lane = threadIdx.x & 63;
    if (node >= N) return;
    int myh = lane >> 3;
    int s0 = rs[node], s1 = rs[node + 1];
    float adn = ad_[(size_t)node * 8 + myh];
    float den = 0.f;
    float2 acc[4] = {};
    const unsigned* hu = (const unsigned*)h;
    int k = s0;
    for (; k + 4 <= s1; k += 4) {
        int i0 = csrc[k], i1 = csrc[k + 1], i2 = csrc[k + 2], i3 = csrc[k + 3];
        float a0 = as_[(size_t)i0 * 8 + myh] + adn;
        float a1 = as_[(size_t)i1 * 8 + myh] + adn;
        float a2 = as_[(size_t)i2 * 8 + myh] + adn;
        float a3 = as_[(size_t)i3 * 8 + myh] + adn;
        a0 = a0 > 0.f ? a0 : 0.2f * a0;  a1 = a1 > 0.f ? a1 : 0.2f * a1;
        a2 = a2 > 0.f ? a2 : 0.2f * a2;  a3 = a3 > 0.f ? a3 : 0.2f * a3;
        float w0 = __expf(fminf(a0, 60.f)), w1 = __expf(fminf(a1, 60.f));
        float w2 = __expf(fminf(a2, 60.f)), w3 = __expf(fminf(a3, 60.f));
        uint4v v0 = *(const uint4v*)(hu + (size_t)i0 * 256 + lane * 4);
        uint4v v1 = *(const uint4v*)(hu + (size_t)i1 * 256 + lane * 4);
        uint4v v2 = *(const uint4v*)(hu + (size_t)i2 * 256 + lane * 4);
        uint4v v3 = *(const uint4v*)(hu + (size_t)i3 * 256 + lane * 4);
        den += (w0 + w1) + (w2 + w3);
#pragma unroll
        for (int j = 0; j < 4; ++j) {
            acc[j].x += w0 * __uint_as_float(v0[j] << 16);
            acc[j].y += w0 * __uint_as_float(v0[j] & 0xffff0000u);
            acc[j].x += w1 * __uint_as_float(v1[j] << 16);
            acc[j].y += w1 * __uint_as_float(v1[j] & 0xffff0000u);
            acc[j].x += w2 * __uint_as_float(v2[j] << 16);
            acc[j].y += w2 * __uint_as_float(v2[j] & 0xffff0000u);
            acc[j].x += w3 * __uint_as_float(v3[j] << 16);
            acc[j].y += w3 * __uint_as_float(v3[j] & 0xffff0000u);
        }
    }
    for (; k < s1; ++k) {
        int i0 = csrc[k];
        float a = as_[(size_t)i0 * 8 + myh] + adn;
        a = a > 0.f ? a : 0.2f * a;
        float w = __expf(fminf(a, 60.f));
        uint4v v0 = *(const uint4v*)(hu + (size_t)i0 * 256 + lane * 4);
        den += w;
#pragma unroll
        for (int j = 0; j < 4; ++j) {
            acc[j].x += w * __uint_as_float(v0[j] << 16);
            acc[j].y += w * __uint_as_float(v0[j] & 0xffff0000u);
        }
    }
    float rden = 1.f / (den + 1e-16f);
    uint4v o;
#pragma unroll
    for (int j = 0; j < 4; ++j) {
        float vlo = acc[j].x * rden + bias[lane * 8 + 2 * j];
        float vhi = acc[j].y * rden + bias[lane * 8 + 2 * j + 1];
        vlo = vlo > 0.f ? vlo : 0.f;
        vhi = vhi > 0.f ? vhi : 0.f;
        o[j] = (unsigned)f2bf(vlo) | ((unsigned)f2bf(vhi) << 16);
    }
    *(uint4v*)(outp + (size_t)node * 512 + lane * 8) = o;
}

// ---------- K7: MFMA GEMM L2 (K=512) + attn2 dots ----------
__global__ __launch_bounds__(256) void gemm_l2_k512(const unsigned short* __restrict__ A,
                                                    const unsigned short* __restrict__ Bfrag,
                                                    unsigned short* __restrict__ Cbf,
                                                    int M,
                                                    const float* __restrict__ avs,
                                                    const float* __restrict__ avd,
                                                    float* __restrict__ as_,
                                                    float* __restrict__ ad_) {
    const int lane = threadIdx.x & 63;
    const int wave = threadIdx.x >> 6;
    const int l15 = lane & 15, l16 = lane >> 4;
    const long rowBase = (long)blockIdx.x * 128 + wave * 32;
    const bfrag8* bp = (const bfrag8*)Bfrag;

    f32x4 acc[2][4];
#pragma unroll
    for (int r = 0; r < 2; ++r)
#pragma unroll
        for (int c = 0; c < 4; ++c)
#pragma unroll
            for (int e = 0; e < 4; ++e) acc[r][c][e] = 0.f;

    long r0 = rowBase + l15;        if (r0 > M - 1) r0 = M - 1;
    long r1 = rowBase + 16 + l15;   if (r1 > M - 1) r1 = M - 1;
    const unsigned short* a0p = A + r0 * 512 + l16 * 8;
    const unsigned short* a1p = A + r1 * 512 + l16 * 8;

    for (int s = 0; s < 16; ++s) {
        bfrag8 a0 = *(const bfrag8*)(a0p + s * 32);
        bfrag8 a1 = *(const bfrag8*)(a1p + s * 32);
        bfrag8 bf0 = bp[(s * 4 + 0) * 64 + lane];
        bfrag8 bf1 = bp[(s * 4 + 1) * 64 + lane];
        bfrag8 bf2 = bp[(s * 4 + 2) * 64 + lane];
        bfrag8 bf3 = bp[(s * 4 + 3) * 64 + lane];
        acc[0][0] = __builtin_amdgcn_mfma_f32_16x16x32_bf16(a0, bf0, acc[0][0], 0, 0, 0);
        acc[1][0] = __builtin_amdgcn_mfma_f32_16x16x32_bf16(a1, bf0, acc[1][0], 0, 0, 0);
        acc[0][1] = __builtin_amdgcn_mfma_f32_16x16x32_bf16(a0, bf1, acc[0][1], 0, 0, 0);
        acc[1][1] = __builtin_amdgcn_mfma_f32_16x16x32_bf16(a1, bf1, acc[1][1], 0, 0, 0);
        acc[0][2] = __builtin_amdgcn_mfma_f32_16x16x32_bf16(a0, bf2, acc[0][2], 0, 0, 0);
        acc[1][2] = __builtin_amdgcn_mfma_f32_16x16x32_bf16(a1, bf2, acc[1][2], 0, 0, 0);
        acc[0][3] = __builtin_amdgcn_mfma_f32_16x16x32_bf16(a0, bf3, acc[0][3], 0, 0, 0);
        acc[1][3] = __builtin_amdgcn_mfma_f32_16x16x32_bf16(a1, bf3, acc[1][3], 0, 0, 0);
    }

    float avsv[4], avdv[4];
#pragma unroll
    for (int c = 0; c < 4; ++c) {
        avsv[c] = avs[c * 16 + l15];
        avdv[c] = avd[c * 16 + l15];
    }

#pragma unroll
    for (int r = 0; r < 2; ++r) {
#pragma unroll
        for (int reg = 0; reg < 4; ++reg) {
            long row = rowBase + r * 16 + l16 * 4 + reg;
            bool ok = row < M;
            float ps = 0.f, pd = 0.f;
#pragma unroll
            for (int c = 0; c < 4; ++c) {
                float v = acc[r][c][reg];
                if (ok) Cbf[row * 64 + c * 16 + l15] = f2bf(v);
                ps += v * avsv[c];
                pd += v * avdv[c];
            }
#pragma unroll
            for (int off = 1; off < 16; off <<= 1) {
                ps += __shfl_xor(ps, off);
                pd += __shfl_xor(pd, off);
            }
            if (l15 == 0 && ok) { as_[row] = ps; ad_[row] = pd; }
        }
    }
}

// ---------- K8: single-head gather -> f32 out ----------
__global__ __launch_bounds__(256) void gather1(const int* __restrict__ csrc,
                                               const int* __restrict__ rs,
                                               const float* __restrict__ as_,
                                               const float* __restrict__ ad_,
                                               const unsigned short* __restrict__ h,
                                               const float* __restrict__ bias,
                                               float* __restrict__ outp, int N) {
    int node = (int)((blockIdx.x * 256u + threadIdx.x) >> 6);
    int lane = threadIdx.x & 63;
    if (node >= N) return;
    int s0 = rs[node], s1 = rs[node + 1];
    float adn = ad_[node];
    float den = 0.f, acc = 0.f;
    int k = s0;
    for (; k + 4 <= s1; k += 4) {
        int i0 = csrc[k], i1 = csrc[k + 1], i2 = csrc[k + 2], i3 = csrc[k + 3];
        float a0 = as_[i0] + adn, a1 = as_[i1] + adn, a2 = as_[i2] + adn, a3 = as_[i3] + adn;
        a0 = a0 > 0.f ? a0 : 0.2f * a0;  a1 = a1 > 0.f ? a1 : 0.2f * a1;
        a2 = a2 > 0.f ? a2 : 0.2f * a2;  a3 = a3 > 0.f ? a3 : 0.2f * a3;
        float w0 = __expf(fminf(a0, 60.f)), w1 = __expf(fminf(a1, 60.f));
        float w2 = __expf(fminf(a2, 60.f)), w3 = __expf(fminf(a3, 60.f));
        float h0 = bf2f(h[(size_t)i0 * 64 + lane]);
        float h1 = bf2f(h[(size_t)i1 * 64 + lane]);
        float h2 = bf2f(h[(size_t)i2 * 64 + lane]);
        float h3 = bf2f(h[(size_t)i3 * 64 + lane]);
        den += (w0 + w1) + (w2 + w3);
        acc += w0 * h0;  acc += w1 * h1;  acc += w2 * h2;  acc += w3 * h3;
    }
    for (; k < s1; ++k) {
        int i0 = csrc[k];
        float a = as_[i0] + adn;
        a = a > 0.f ? a : 0.2f * a;
        float w = __expf(fminf(a, 60.f));
        den += w;
        acc += w * bf2f(h[(size_t)i0 * 64 + lane]);
    }
    float v = acc / (den + 1e-16f) + bias[lane];
    outp[(size_t)node * 64 + lane] = v > 0.f ? v : 0.f;
}

// ---------- K9: fused mean-pool + readout ----------
__global__ __launch_bounds__(256) void pool_readout(const float* __restrict__ h2,
                                                    const int* __restrict__ gstart,
                                                    const float* __restrict__ Wf,
                                                    const float* __restrict__ bf,
                                                    float* __restrict__ out, int G) {
    int g = (int)((blockIdx.x * 256u + threadIdx.x) >> 6);
    int lane = threadIdx.x & 63;
    if (g >= G) return;
    int s0 = gstart[g], s1 = gstart[g + 1];
    float acc = 0.f;
    int i = s0;
    for (; i + 2 <= s1; i += 2) {
        acc += h2[(size_t)i * 64 + lane];
        acc += h2[(size_t)(i + 1) * 64 + lane];
    }
    if (i < s1) acc += h2[(size_t)i * 64 + lane];
    float c = (float)(s1 - s0);
    c = c < 1.f ? 1.f : c;
    float v = acc / c * Wf[lane];
#pragma unroll
    for (int off = 32; off; off >>= 1) v += __shfl_xor(v, off);
    if (lane == 0) out[g] = v + bf[0];
}

extern "C" void kernel_launch(void* const* d_in, const int* in_sizes, int n_in,
                              void* d_out, int out_size, void* d_ws, size_t ws_size,
                              hipStream_t stream) {
    const float* x        = (const float*)d_in[0];
    const int*   ei       = (const int*)d_in[1];
    const int*   batch    = (const int*)d_in[2];
    const float* W1       = (const float*)d_in[3];
    const float* att_src1 = (const float*)d_in[4];
    const float* att_dst1 = (const float*)d_in[5];
    const float* b1       = (const float*)d_in[6];
    const float* W2       = (const float*)d_in[7];
    const float* att_src2 = (const float*)d_in[8];
    const float* att_dst2 = (const float*)d_in[9];
    const float* b2       = (const float*)d_in[10];
    const float* Wf       = (const float*)d_in[11];
    const float* bf       = (const float*)d_in[12];
    float* out = (float*)d_out;

    const int N = in_sizes[2];        // 100000
    const int E = in_sizes[1] / 2;    // 400000
    const int G = out_size;           // 4096

    const int nb = (N + SCAN_BLK - 1) / SCAN_BLK;
    const int nodeWaveGrid = (int)(((size_t)N * 64 + 255) / 256);
    const int edgeGrid = (E + N + 255) / 256;
    const int gemmGrid128 = (N + 127) / 128;
    const int gemmGrid64 = (N + 63) / 64;

    // ---- workspace layout ----
    char* base = (char*)d_ws;
    size_t off = 0;
    auto alloc = [&](size_t bytes) { char* p = base + off; off += (bytes + 255) & ~255llu; return p; };
    unsigned short* wf1   = (unsigned short*)alloc(131072);
    unsigned short* wf2   = (unsigned short*)alloc(65536);
    float* as1            = (float*)alloc((size_t)N * 8 * 4);
    float* ad1            = (float*)alloc((size_t)N * 8 * 4);
    float* as2            = (float*)alloc((size_t)N * 4);
    float* ad2            = (float*)alloc((size_t)N * 4);
    int*   cnt_i          = (int*)alloc((size_t)N * 4);
    int*   rs             = (int*)alloc((size_t)(N + 1) * 4);
    int*   csrc           = (int*)alloc((size_t)(E + N) * 4);
    int*   bsum           = (int*)alloc(1024);
    int*   gstart         = (int*)alloc((size_t)(G + 1) * 4);
    float* ob2            = (float*)alloc((size_t)N * 64 * 4);
    unsigned short* h2bf  = (unsigned short*)alloc((size_t)N * 64 * 2);
    unsigned short* h1_bf = (unsigned short*)alloc((size_t)N * 512 * 2);
    unsigned short* ob1_bf= (unsigned short*)alloc((size_t)N * 512 * 2);
    (void)ws_size;

    // ---- K1: prologue (zero + weight pack + gstart) ----
    {
        int gsBlocks = (N + 256) / 256 + 1;
        prologue<<<896 + gsBlocks, 256, 0, stream>>>(cnt_i, W1, W2, wf1, wf2,
                                                     batch, gstart, rs, N, G, E);
    }

    // ---- K2: layer-1 GEMM (64-row blocks, LDS-staged stores) + histogram tail ----
    gemm_l1_hist<<<gemmGrid64 + edgeGrid, 256, 0, stream>>>(
        x, wf1, h1_bf, N, att_src1, att_dst1, as1, ad1,
        gemmGrid64, ei, cnt_i, E);

    // ---- K3-K5: scan + scatter ----
    scan1<<<nb, 256, 0, stream>>>(cnt_i, rs, bsum, N);
    scan_fix<<<(N + 255) / 256, 256, 0, stream>>>(rs, bsum, N);
    scatter_cd<<<edgeGrid, 256, 0, stream>>>(ei, rs, cnt_i, csrc, E, N);

    // ---- K6: layer-1 aggregation (all heads, single pass) ----
    gather8<<<nodeWaveGrid, 256, 0, stream>>>(csrc, rs, as1, ad1, h1_bf, b1, ob1_bf, N);

    // ---- K7: layer-2 GEMM (K=512) + attn2 dots ----
    gemm_l2_k512<<<gemmGrid128, 256, 0, stream>>>(ob1_bf, wf2, h2bf, N,
                                                  att_src2, att_dst2, as2, ad2);

    // ---- K8: layer-2 aggregation ----
    gather1<<<nodeWaveGrid, 256, 0, stream>>>(csrc, rs, as2, ad2, h2bf, b2, ob2, N);

    // ---- K9: pool + readout ----
    pool_readout<<<(G * 64 + 255) / 256, 256, 0, stream>>>(ob2, gstart, Wf, bf, out, G);
}